// Round 1
// baseline (10591.951 us; speedup 1.0000x reference)
//
#include <hip/hip_runtime.h>

#define THREADS 256
#define ROWS 16
#define DD 512
#define HIDN 512
#define TT 16
#define OUTN 7
#define XSTR 516   // padded xs row stride in floats (2064 B): A-frag reads 2-way banks max

typedef __attribute__((ext_vector_type(8))) _Float16 half8;
typedef __attribute__((ext_vector_type(4))) float f32x4;

// async global->LDS, 16B per lane; LDS dest = wave-uniform base (+ lane*16 by HW)
#define GLD_LDS(g, l) __builtin_amdgcn_global_load_lds(                     \
    (const __attribute__((address_space(1))) void*)(g),                     \
    (__attribute__((address_space(3))) void*)(l), 16, 0, 0)

// ---- weight pre-pack: fp32 -> (hi,lo) f16 in MFMA B-fragment order -----------
// cell = (ct, ks, lane); element j = W[k = ks*32 + (lane>>4)*8 + j][col],
// col = ct'*16 + (lane&15);  ct<32 -> Wgc tile ct, ct>=32 -> Wd1 top tile ct-32.
// Requires ws_size >= 2 MiB.
__global__ void pack_w(const float* __restrict__ Wgc, const float* __restrict__ Wd1,
                       _Float16* __restrict__ Whi, _Float16* __restrict__ Wlo)
{
    const int cell = blockIdx.x * blockDim.x + threadIdx.x;    // 64*16*64 = 65536
    const int lane = cell & 63;
    const int ks   = (cell >> 6) & 15;
    const int ct   = cell >> 10;
    const float* W = (ct < 32) ? Wgc : Wd1;
    const int col  = ((ct < 32) ? ct : ct - 32) * 16 + (lane & 15);
    const int k0   = ks * 32 + ((lane >> 4) << 3);
    half8 vh, vl;
#pragma unroll
    for (int j = 0; j < 8; ++j) {
        const float w = W[(size_t)(k0 + j) * HIDN + col];
        const _Float16 h = (_Float16)w;
        vh[j] = h;
        vl[j] = (_Float16)(w - (float)h);     // exact residual, rounded to f16
    }
    *reinterpret_cast<half8*>(Whi + (size_t)cell * 8) = vh;
    *reinterpret_cast<half8*>(Wlo + (size_t)cell * 8) = vl;
}

// One block owns ROWS batch rows for the whole T-loop. Dense xt@[Wgc|Wd1_top]
// is split-precision f16 hi/lo MFMA (3 products ~= fp32). LIF1/LIF3 run in the
// MFMA C-layout (row=(lane>>4)*4+j, col=ct*16+(lane&15)); spike bits are
// transformed to the row-major 8xu64 masks only when spikes exist (rare).
// Sparse pc/d1-bottom layers keep the bitmask-driven weight-row accumulation.
__global__ __launch_bounds__(THREADS, 2)
void snn_fused_kernel(const float* __restrict__ x,
                      const _Float16* __restrict__ Whi, const _Float16* __restrict__ Wlo,
                      const float* __restrict__ bgc,
                      const float* __restrict__ Wpc, const float* __restrict__ bpc,
                      const float* __restrict__ Wd1, const float* __restrict__ bd1p,
                      const float* __restrict__ Wd2, const float* __restrict__ bd2,
                      float* __restrict__ out, int B)
{
    __shared__ float xs[ROWS * XSTR];                       // 33 KB fp32 x-tile (padded)
    __shared__ __align__(16) float upool[8192];             // 32 KB: A-frags (hi|lo) U pc_c
    __shared__ unsigned long long bits1[ROWS][8];
    __shared__ unsigned long long bits2[ROWS][8];
    __shared__ unsigned long long bits3[ROWS][8];
    __shared__ unsigned int rowflag[3];

    _Float16* const Ahi = reinterpret_cast<_Float16*>(upool);   // 8192 halves (16 KB)
    _Float16* const Alo = Ahi + ROWS * DD;                      // 8192 halves (16 KB)
    float* const pc_c   = upool;                                // 16x512 f32, time-shared

    const int tid  = threadIdx.x;
    const int lane = tid & 63;
    const int wave = tid >> 6;
    const size_t row0 = (size_t)blockIdx.x * ROWS;
    const int cb = wave << 3;            // this wave's col-tile base (8 gc + 8 d1 tiles)

    float m1[8][4], m3[8][4], m2a[ROWS], m2b[ROWS];
    f32x4 d1acc[8];
#pragma unroll
    for (int c = 0; c < 8; ++c)
#pragma unroll
        for (int j = 0; j < 4; ++j) { m1[c][j] = 0.f; m3[c][j] = 0.f; }
#pragma unroll
    for (int r = 0; r < ROWS; ++r) { m2a[r] = 0.f; m2b[r] = 0.f; }

    float bgv[8], bdv[8];
#pragma unroll
    for (int c = 0; c < 8; ++c) {
        bgv[c] = bgc[(cb + c) * 16 + (lane & 15)];
        bdv[c] = bd1p[(cb + c) * 16 + (lane & 15)];
    }
    const float bp0 = bpc[tid], bp1 = bpc[tid + 256];

    float out_acc = 0.f;
    const int orow = tid / OUTN;
    const int ocol = tid - orow * OUTN;
    const bool owrite = (tid < ROWS * OUTN);

    const half8* const Bh8 = reinterpret_cast<const half8*>(Whi);
    const half8* const Bl8 = reinterpret_cast<const half8*>(Wlo);

    // LIF + spike-pack for a neuron quad in MFMA C-layout; transforms the 4
    // ballots (4 rows x 16 cols each) into row-major 64-bit words via atomicOr.
    auto lif_pack = [&](int ct, const f32x4& acc, float bias, float (&m)[4],
                        unsigned long long (&bits)[ROWS][8], unsigned int* flag) {
        unsigned long long kb[4];
#pragma unroll
        for (int j = 0; j < 4; ++j) {
            const float I = acc[j] + bias;
            const float v = m[j] + (I - m[j]) * 0.5f;
            const bool s = (v - 1.0f) > 0.0f;
            m[j] = s ? 0.0f : v;
            kb[j] = __ballot(s);
        }
        if (lane == 0 && (kb[0] | kb[1] | kb[2] | kb[3])) {
            const int wd = ct >> 2;
            const int sh = (ct & 3) << 4;
            unsigned int rmask = 0;
#pragma unroll
            for (int j = 0; j < 4; ++j)
#pragma unroll
                for (int g = 0; g < 4; ++g) {
                    const unsigned long long ch = (kb[j] >> (g << 4)) & 0xFFFFull;
                    if (ch) {
                        atomicOr(&bits[(g << 2) + j][wd], ch << sh);
                        rmask |= 1u << ((g << 2) + j);
                    }
                }
            atomicOr(flag, rmask);
        }
    };

    // dense 16x512 x 512x16 over two col-tiles; fp32-accurate 3-product hi/lo
    auto dense_pair = [&](int ctA, int ctB, f32x4& rA, f32x4& rB) {
        f32x4 aA = {0.f, 0.f, 0.f, 0.f}, aB = {0.f, 0.f, 0.f, 0.f};
        const half8* pAh = Bh8 + (size_t)ctA * (16 * 64) + lane;
        const half8* pAl = Bl8 + (size_t)ctA * (16 * 64) + lane;
        const half8* pBh = Bh8 + (size_t)ctB * (16 * 64) + lane;
        const half8* pBl = Bl8 + (size_t)ctB * (16 * 64) + lane;
#pragma unroll
        for (int ks = 0; ks < 16; ++ks) {
            const half8 ah = *reinterpret_cast<const half8*>(Ahi + (ks * 64 + lane) * 8);
            const half8 al = *reinterpret_cast<const half8*>(Alo + (ks * 64 + lane) * 8);
            const half8 bhA = pAh[ks * 64], blA = pAl[ks * 64];
            const half8 bhB = pBh[ks * 64], blB = pBl[ks * 64];
            aA = __builtin_amdgcn_mfma_f32_16x16x32_f16(ah, bhA, aA, 0, 0, 0);
            aB = __builtin_amdgcn_mfma_f32_16x16x32_f16(ah, bhB, aB, 0, 0, 0);
            aA = __builtin_amdgcn_mfma_f32_16x16x32_f16(al, bhA, aA, 0, 0, 0);
            aB = __builtin_amdgcn_mfma_f32_16x16x32_f16(al, bhB, aB, 0, 0, 0);
            aA = __builtin_amdgcn_mfma_f32_16x16x32_f16(ah, blA, aA, 0, 0, 0);
            aB = __builtin_amdgcn_mfma_f32_16x16x32_f16(ah, blB, aB, 0, 0, 0);
        }
        rA = aA; rB = aB;
    };

    // ---- prologue: zero masks/flags, async-stage xs for t=0 (padded rows)
    if (tid < 128) reinterpret_cast<unsigned long long*>(bits1)[tid] = 0ull;
    if (tid < 3) rowflag[tid] = 0u;
    {
        const float* src = x + row0 * DD;
#pragma unroll
        for (int u = 0; u < 8; ++u) {
            const int c = (u << 2) + wave;               // 1 KB chunk id
            GLD_LDS(src + (c << 8) + (lane << 2),
                    xs + (c >> 1) * XSTR + (c & 1) * 256);
        }
    }
    __syncthreads();

#pragma unroll 1
    for (int t = 0; t < TT; ++t) {
        // ===== S1: xs(fp32) -> A-fragments (hi,lo f16) in upool ===============
#pragma unroll
        for (int i = 0; i < 4; ++i) {
            const int cell = tid + (i << 8);
            const int ln = cell & 63, ks = cell >> 6;
            const float* xp = &xs[(ln & 15) * XSTR + ks * 32 + ((ln >> 4) << 3)];
            const float4 f0 = *reinterpret_cast<const float4*>(xp);
            const float4 f1 = *reinterpret_cast<const float4*>(xp + 4);
            const float f[8] = {f0.x, f0.y, f0.z, f0.w, f1.x, f1.y, f1.z, f1.w};
            half8 vh, vl;
#pragma unroll
            for (int j = 0; j < 8; ++j) {
                const _Float16 h = (_Float16)f[j];
                vh[j] = h;
                vl[j] = (_Float16)(f[j] - (float)h);
            }
            *reinterpret_cast<half8*>(Ahi + cell * 8) = vh;
            *reinterpret_cast<half8*>(Alo + cell * 8) = vl;
        }
        __syncthreads();                                   // B1: A-frags ready

        // ===== S2: dense MFMA (gc -> LIF1 -> bits1; d1 -> d1acc) ==============
        if (tid < 128) reinterpret_cast<unsigned long long*>(bits3)[tid] = 0ull;
        if (tid == 0) rowflag[2] = 0u;
        if (t + 1 < TT) {                                  // async-stage next x-tile
            const float* src = x + (((size_t)(t + 1) * B) + row0) * DD;
#pragma unroll
            for (int u = 0; u < 8; ++u) {
                const int c = (u << 2) + wave;
                GLD_LDS(src + (c << 8) + (lane << 2),
                        xs + (c >> 1) * XSTR + (c & 1) * 256);
            }
        }
        {
            f32x4 aA, aB;
            dense_pair(cb + 0, cb + 1, aA, aB);
            lif_pack(cb + 0, aA, bgv[0], m1[0], bits1, &rowflag[0]);
            lif_pack(cb + 1, aB, bgv[1], m1[1], bits1, &rowflag[0]);
            dense_pair(cb + 2, cb + 3, aA, aB);
            lif_pack(cb + 2, aA, bgv[2], m1[2], bits1, &rowflag[0]);
            lif_pack(cb + 3, aB, bgv[3], m1[3], bits1, &rowflag[0]);
            dense_pair(cb + 4, cb + 5, aA, aB);
            lif_pack(cb + 4, aA, bgv[4], m1[4], bits1, &rowflag[0]);
            lif_pack(cb + 5, aB, bgv[5], m1[5], bits1, &rowflag[0]);
            dense_pair(cb + 6, cb + 7, aA, aB);
            lif_pack(cb + 6, aA, bgv[6], m1[6], bits1, &rowflag[0]);
            lif_pack(cb + 7, aB, bgv[7], m1[7], bits1, &rowflag[0]);
            dense_pair(32 + cb + 0, 32 + cb + 1, d1acc[0], d1acc[1]);
            dense_pair(32 + cb + 2, 32 + cb + 3, d1acc[2], d1acc[3]);
            dense_pair(32 + cb + 4, 32 + cb + 5, d1acc[4], d1acc[5]);
            dense_pair(32 + cb + 6, 32 + cb + 7, d1acc[6], d1acc[7]);
        }
        __syncthreads();                                   // B2: bits1 complete

        // ===== S3: layer 2 (pc): sparse bits1 -> bits2 ========================
        {
            const unsigned int rf = rowflag[0];
#pragma unroll
            for (int r = 0; r < ROWS; ++r) {
                float p0 = bp0, p1 = bp1;
                if (rf & (1u << r)) {
#pragma unroll 1
                    for (int w2 = 0; w2 < 8; ++w2) {
                        unsigned long long mm = bits1[r][w2];
                        while (mm) {
                            const int b = __builtin_ctzll(mm); mm &= (mm - 1);
                            const float* wp = Wpc + (size_t)((w2 << 6) + b) * HIDN + tid;
                            p0 += wp[0]; p1 += wp[256];
                        }
                    }
                }
                const float v0 = m2a[r] + (p0 - m2a[r]) * 0.5f;
                const bool s0 = (v0 - 1.0f) > 0.0f;
                m2a[r] = s0 ? 0.0f : v0;
                const unsigned long long k0 = __ballot(s0);
                const float v1 = m2b[r] + (p1 - m2b[r]) * 0.5f;
                const bool s1 = (v1 - 1.0f) > 0.0f;
                m2b[r] = s1 ? 0.0f : v1;
                const unsigned long long k1 = __ballot(s1);
                if (lane == 0) {
                    bits2[r][wave] = k0; bits2[r][4 + wave] = k1;
                    if (k0 | k1) atomicOr(&rowflag[1], 1u << r);
                }
            }
        }
        __syncthreads();                                   // B3: bits2 complete

        // ===== S4: pc spikes -> pc_c (LDS, overlays A-frags); zero bits1 ======
        if (tid < 128) reinterpret_cast<unsigned long long*>(bits1)[tid] = 0ull;
        if (tid == 0) rowflag[0] = 0u;
        const unsigned int rf1 = rowflag[1];
        if (rf1) {
#pragma unroll 1
            for (int r = 0; r < ROWS; ++r) {
                if (!(rf1 & (1u << r))) continue;
                float p0 = 0.f, p1 = 0.f;
#pragma unroll 1
                for (int w2 = 0; w2 < 8; ++w2) {
                    unsigned long long mm = bits2[r][w2];
                    while (mm) {
                        const int b = __builtin_ctzll(mm); mm &= (mm - 1);
                        const float* wp = Wd1 + (size_t)(DD + (w2 << 6) + b) * HIDN + tid;
                        p0 += wp[0]; p1 += wp[256];
                    }
                }
                pc_c[(r << 9) + tid] = p0;
                pc_c[(r << 9) + tid + 256] = p1;
            }
            __syncthreads();                               // B4 (only when pc spiked)
        }

        // ===== S5: layer 3 LIF in MFMA layout -> bits3 ========================
        {
            auto lif3 = [&](const f32x4& acc, float bias, int ct3, float (&m)[4]) {
                f32x4 I;
#pragma unroll
                for (int j = 0; j < 4; ++j) {
                    float Ij = acc[j] + bias;
                    const int row = ((lane >> 4) << 2) + j;
                    if (rf1 & (1u << row))
                        Ij += pc_c[(row << 9) + (ct3 << 4) + (lane & 15)];
                    I[j] = Ij;
                }
                lif_pack(ct3, I, 0.f, m, bits3, &rowflag[2]);
            };
            lif3(d1acc[0], bdv[0], cb + 0, m3[0]);
            lif3(d1acc[1], bdv[1], cb + 1, m3[1]);
            lif3(d1acc[2], bdv[2], cb + 2, m3[2]);
            lif3(d1acc[3], bdv[3], cb + 3, m3[3]);
            lif3(d1acc[4], bdv[4], cb + 4, m3[4]);
            lif3(d1acc[5], bdv[5], cb + 5, m3[5]);
            lif3(d1acc[6], bdv[6], cb + 6, m3[6]);
            lif3(d1acc[7], bdv[7], cb + 7, m3[7]);
        }
        __syncthreads();                                   // B5: bits3 complete

        // ===== S6: output accumulation over s3 spikes =========================
        {
            const unsigned int rf2 = rowflag[2];
            if (owrite && (rf2 & (1u << orow))) {
#pragma unroll 1
                for (int w2 = 0; w2 < 8; ++w2) {
                    unsigned long long mm = bits3[orow][w2];
                    while (mm) {
                        const int b = __builtin_ctzll(mm); mm &= (mm - 1);
                        out_acc += Wd2[(size_t)((w2 << 6) + b) * OUTN + ocol];
                    }
                }
            }
            if (tid == 0) rowflag[1] = 0u;
        }
        // B1 of t+1 orders S6 reads before the next bits3 zeroing (S2) and the
        // next upool overwrite (S1 writes A-frags only after B5).
    }

    if (owrite) out[(row0 + orow) * OUTN + ocol] = out_acc * 0.0625f + bd2[ocol];
}

extern "C" void kernel_launch(void* const* d_in, const int* in_sizes, int n_in,
                              void* d_out, int out_size, void* d_ws, size_t ws_size,
                              hipStream_t stream) {
    const float* x   = (const float*)d_in[0];
    const float* Wgc = (const float*)d_in[1];
    const float* bgc = (const float*)d_in[2];
    const float* Wpc = (const float*)d_in[3];
    const float* bpc = (const float*)d_in[4];
    const float* Wd1 = (const float*)d_in[5];
    const float* bd1 = (const float*)d_in[6];
    const float* Wd2 = (const float*)d_in[7];
    const float* bd2 = (const float*)d_in[8];
    const int B = in_sizes[0] / (TT * DD);

    _Float16* Whi = reinterpret_cast<_Float16*>(d_ws);          // 1 MiB
    _Float16* Wlo = Whi + 64 * 16 * 64 * 8;                     // 1 MiB (ws >= 2 MiB)

    hipLaunchKernelGGL(pack_w, dim3(256), dim3(256), 0, stream, Wgc, Wd1, Whi, Wlo);
    hipLaunchKernelGGL(snn_fused_kernel, dim3(B / ROWS), dim3(THREADS), 0, stream,
                       x, Whi, Wlo, bgc, Wpc, bpc, Wd1, bd1, Wd2, bd2,
                       (float*)d_out, B);
}

// Round 3
// 1923.691 us; speedup vs baseline: 5.5061x; 5.5061x over previous
//
#include <hip/hip_runtime.h>

#define TT 16
#define DD 512
#define HIDN 512
#define OUTN 7
#define NTOT 1024          // G cols: gc pre-act 0..511, d1-top pre-act 512..1023
#define R2 8               // rows per block in recurrent kernel

typedef __attribute__((ext_vector_type(8))) _Float16 half8;
typedef __attribute__((ext_vector_type(4))) _Float16 half4;
typedef __attribute__((ext_vector_type(4))) float f32x4;

// async global->LDS, 16B/lane; LDS dest = wave-uniform base (+ lane*16 by HW)
#define GLD_LDS(g, l) __builtin_amdgcn_global_load_lds(                     \
    (const __attribute__((address_space(1))) void*)(g),                     \
    (__attribute__((address_space(3))) void*)(l), 16, 0, 0)

// ---- weight pre-pack: fp32 -> (hi,lo) f16 in MFMA B-fragment order ----------
// cell = (ct, ks, lane); elem j = W[k = ks*32 + (lane>>4)*8 + j][col],
// col = ct'*16 + (lane&15); ct<32 -> Wgc tile ct, ct>=32 -> Wd1-top tile ct-32.
__global__ void pack_w(const float* __restrict__ Wgc, const float* __restrict__ Wd1,
                       _Float16* __restrict__ Whi, _Float16* __restrict__ Wlo)
{
    const int cell = blockIdx.x * blockDim.x + threadIdx.x;    // 64*16*64 = 65536
    const int lane = cell & 63;
    const int ks   = (cell >> 6) & 15;
    const int ct   = cell >> 10;
    const float* W = (ct < 32) ? Wgc : Wd1;
    const int col  = ((ct < 32) ? ct : ct - 32) * 16 + (lane & 15);
    const int k0   = ks * 32 + ((lane >> 4) << 3);
    half8 vh, vl;
#pragma unroll
    for (int j = 0; j < 8; ++j) {
        const float w = W[(size_t)(k0 + j) * HIDN + col];
        const _Float16 h = (_Float16)w;
        vh[j] = h;
        vl[j] = (_Float16)(w - (float)h);
    }
    *reinterpret_cast<half8*>(Whi + (size_t)cell * 8) = vh;
    *reinterpret_cast<half8*>(Wlo + (size_t)cell * 8) = vl;
}

// ---- Phase 1: G = X_chunk @ [Wgc | Wd1top]  (fp32 via f16 hi/lo, 3 products) -
// 128x128 tile, BK=32, 256 thr = 4 waves (2x2), 4x4 16x16x32 frags per wave.
// grid = (8, chb/128, TT); blockIdx.z = timestep (no div needed).
__global__ __launch_bounds__(256, 2)
void gemm_pre(const float* __restrict__ x,
              const _Float16* __restrict__ Whi, const _Float16* __restrict__ Wlo,
              float* __restrict__ G, int B, int c0, int chb)
{
    __shared__ __align__(16) _Float16 Ah[2][4096];   // [buf][rowgrp(8)][lane(64)][8]
    __shared__ __align__(16) _Float16 Al[2][4096];
    __shared__ __align__(16) _Float16 Bh[2][4096];   // [buf][colgrp(8)][lane(64)][8]
    __shared__ __align__(16) _Float16 Bl[2][4096];

    const int tid  = threadIdx.x;
    const int lane = tid & 63;
    const int wave = tid >> 6;
    const int wr   = wave >> 1;
    const int wc   = wave & 1;
    const int t    = blockIdx.z;
    const size_t mrow = (size_t)blockIdx.y * 128;     // chunk-local row
    const int ct0 = blockIdx.x * 8;                   // first 16-col tile

    const float* xb = x + ((size_t)t * B + (size_t)c0 + mrow) * DD;
    float* Gb = G + ((size_t)t * chb + mrow) * NTOT;

    f32x4 acc[4][4];
#pragma unroll
    for (int g = 0; g < 4; ++g)
#pragma unroll
        for (int c = 0; c < 4; ++c) acc[g][c] = (f32x4){0.f, 0.f, 0.f, 0.f};

    float4 ar[4];                       // A-chunk staging regs (consumed next iter)
    const int row_u0 = tid >> 3;        // A map: u -> row=row_u0+u*32
    const int fg = tid & 7;             //        k0=fg*4 within 32-wide K chunk

#define LOAD_A(kc)                                                            \
    {                                                                         \
        _Pragma("unroll")                                                     \
        for (int u = 0; u < 4; ++u)                                           \
            ar[u] = *reinterpret_cast<const float4*>(                         \
                xb + (size_t)(row_u0 + u * 32) * DD + (kc) * 32 + (fg << 2)); \
    }

#define CVT_WRITE(BUF)                                                        \
    {                                                                         \
        _Pragma("unroll")                                                     \
        for (int u = 0; u < 4; ++u) {                                         \
            const int row = row_u0 + u * 32;                                  \
            const int gg = row >> 4;                                          \
            const int ld = (row & 15) | ((fg >> 1) << 4);                     \
            const int offs = ((gg << 6) + ld) * 8 + ((fg & 1) << 2);          \
            const float fv[4] = {ar[u].x, ar[u].y, ar[u].z, ar[u].w};         \
            half4 vh, vl;                                                     \
            _Pragma("unroll")                                                 \
            for (int j = 0; j < 4; ++j) {                                     \
                const _Float16 h = (_Float16)fv[j];                           \
                vh[j] = h; vl[j] = (_Float16)(fv[j] - (float)h);              \
            }                                                                 \
            *reinterpret_cast<half4*>(&Ah[BUF][offs]) = vh;                   \
            *reinterpret_cast<half4*>(&Al[BUF][offs]) = vl;                   \
        }                                                                     \
    }

#define STAGE_B(kc, BUF)                                                      \
    {                                                                         \
        const int cga = wave << 1, cgb = cga + 1;                             \
        const size_t sa = ((size_t)((ct0 + cga) * 16 + (kc)) * 64 + lane) * 8;\
        const size_t sb = ((size_t)((ct0 + cgb) * 16 + (kc)) * 64 + lane) * 8;\
        GLD_LDS(Whi + sa, &Bh[BUF][cga << 9]);                                \
        GLD_LDS(Wlo + sa, &Bl[BUF][cga << 9]);                                \
        GLD_LDS(Whi + sb, &Bh[BUF][cgb << 9]);                                \
        GLD_LDS(Wlo + sb, &Bl[BUF][cgb << 9]);                                \
    }

    // per-c B-frag loads keep live frag regs low (fits launch_bounds(256,2))
#define COMPUTE(BUF)                                                          \
    {                                                                         \
        half8 af[4], alf[4];                                                  \
        _Pragma("unroll")                                                     \
        for (int g = 0; g < 4; ++g) {                                         \
            const int o = (((wr << 2) + g) * 64 + lane) * 8;                  \
            af[g]  = *reinterpret_cast<const half8*>(&Ah[BUF][o]);            \
            alf[g] = *reinterpret_cast<const half8*>(&Al[BUF][o]);            \
        }                                                                     \
        _Pragma("unroll")                                                     \
        for (int c = 0; c < 4; ++c) {                                         \
            const int o = (((wc << 2) + c) * 64 + lane) * 8;                  \
            const half8 bf  = *reinterpret_cast<const half8*>(&Bh[BUF][o]);   \
            const half8 blf = *reinterpret_cast<const half8*>(&Bl[BUF][o]);   \
            _Pragma("unroll")                                                 \
            for (int g = 0; g < 4; ++g) {                                     \
                acc[g][c] = __builtin_amdgcn_mfma_f32_16x16x32_f16(af[g],  bf,  acc[g][c], 0, 0, 0); \
                acc[g][c] = __builtin_amdgcn_mfma_f32_16x16x32_f16(alf[g], bf,  acc[g][c], 0, 0, 0); \
                acc[g][c] = __builtin_amdgcn_mfma_f32_16x16x32_f16(af[g],  blf, acc[g][c], 0, 0, 0); \
            }                                                                 \
        }                                                                     \
    }

    // prologue: buf0 <- K-chunk 0; ar <- chunk 1
    LOAD_A(0);
    STAGE_B(0, 0);
    CVT_WRITE(0);
    LOAD_A(1);
    __syncthreads();

#pragma unroll 1
    for (int kh = 0; kh < 8; ++kh) {
        // even step: compute buf0 (chunk 2kh); stage chunk 2kh+1 -> buf1
        CVT_WRITE(1);
        STAGE_B(2 * kh + 1, 1);
        if (2 * kh + 2 < 16) LOAD_A(2 * kh + 2);
        COMPUTE(0);
        __syncthreads();
        // odd step: compute buf1 (chunk 2kh+1); stage chunk 2kh+2 -> buf0
        if (2 * kh + 2 < 16) {
            CVT_WRITE(0);
            STAGE_B(2 * kh + 2, 0);
        }
        if (2 * kh + 3 < 16) LOAD_A(2 * kh + 3);
        COMPUTE(1);
        __syncthreads();
    }

    // epilogue: C layout row=(lane>>4)*4+j, col=lane&15 (m89-verified)
    const int r0 = (lane >> 4) << 2;
    const int cl = lane & 15;
#pragma unroll
    for (int g = 0; g < 4; ++g)
#pragma unroll
        for (int c = 0; c < 4; ++c) {
            float* gp = Gb + (size_t)((wr << 6) + (g << 4) + r0) * NTOT
                           + (blockIdx.x << 7) + (wc << 6) + (c << 4) + cl;
#pragma unroll
            for (int j = 0; j < 4; ++j) gp[(size_t)j * NTOT] = acc[g][c][j];
        }
#undef LOAD_A
#undef CVT_WRITE
#undef STAGE_B
#undef COMPUTE
}

// ---- Phase 2: recurrent LIF + sparse spike-driven layers over G --------------
__global__ __launch_bounds__(256, 4)
void snn_recur(const float* __restrict__ G, const float* __restrict__ bgc,
               const float* __restrict__ Wpc, const float* __restrict__ bpc,
               const float* __restrict__ Wd1, const float* __restrict__ bd1p,
               const float* __restrict__ Wd2, const float* __restrict__ bd2,
               float* __restrict__ out, int c0, int chb)
{
    __shared__ unsigned long long bits1[R2][8];
    __shared__ unsigned long long bits2[R2][8];
    __shared__ unsigned long long bits3[R2][8];
    __shared__ unsigned int rowflag[3];

    const int tid  = threadIdx.x;
    const int lane = tid & 63;
    const int wave = tid >> 6;
    const int row0l = blockIdx.x * R2;                 // chunk-local base row

    float m1a[R2], m1b[R2], m2a[R2], m2b[R2], m3a[R2], m3b[R2];
#pragma unroll
    for (int r = 0; r < R2; ++r) {
        m1a[r] = 0.f; m1b[r] = 0.f; m2a[r] = 0.f;
        m2b[r] = 0.f; m3a[r] = 0.f; m3b[r] = 0.f;
    }

    const float bg0 = bgc[tid],  bg1 = bgc[tid + 256];
    const float bp0 = bpc[tid],  bp1 = bpc[tid + 256];
    const float bd0 = bd1p[tid], bd1v = bd1p[tid + 256];

    float out_acc = 0.f;
    const int orow = tid / OUTN;
    const int ocol = tid - orow * OUTN;
    const bool owrite = (tid < R2 * OUTN);

    if (tid < 3) rowflag[tid] = 0u;
    __syncthreads();

#pragma unroll 1
    for (int t = 0; t < TT; ++t) {
        const float* Gt = G + ((size_t)t * chb + row0l) * NTOT;
        float ga[R2], gb[R2], g2[R2], g3[R2];
#pragma unroll
        for (int r = 0; r < R2; ++r) {
            const float* gp = Gt + (size_t)r * NTOT + tid;
            ga[r] = gp[0]; gb[r] = gp[256]; g2[r] = gp[512]; g3[r] = gp[768];
        }

        // ===== LIF layer 1 (gc) -> bits1 + rowflag[0] =========================
#pragma unroll
        for (int r = 0; r < R2; ++r) {
            const float v0 = m1a[r] + ((ga[r] + bg0) - m1a[r]) * 0.5f;
            const bool s0 = (v0 - 1.0f) > 0.0f;
            m1a[r] = s0 ? 0.0f : v0;
            const unsigned long long k0 = __ballot(s0);
            const float v1 = m1b[r] + ((gb[r] + bg1) - m1b[r]) * 0.5f;
            const bool s1 = (v1 - 1.0f) > 0.0f;
            m1b[r] = s1 ? 0.0f : v1;
            const unsigned long long k1 = __ballot(s1);
            if (lane == 0) {
                bits1[r][wave] = k0; bits1[r][4 + wave] = k1;
                if (k0 | k1) atomicOr(&rowflag[0], 1u << r);
            }
        }
        __syncthreads();                                   // barrier A
        if (tid == 0) rowflag[2] = 0u;

        // ===== layer 2 (pc): sparse bits1 -> bits2 + rowflag[1] ===============
        {
            const unsigned int rf = rowflag[0];
#pragma unroll
            for (int r = 0; r < R2; ++r) {
                float p0 = bp0, p1 = bp1;
                if (rf & (1u << r)) {
#pragma unroll 1
                    for (int w = 0; w < 8; ++w) {
                        unsigned long long mm = bits1[r][w];
                        while (mm) {
                            const int b = __builtin_ctzll(mm); mm &= (mm - 1);
                            const float* wp = Wpc + (size_t)((w << 6) + b) * HIDN + tid;
                            p0 += wp[0]; p1 += wp[256];
                        }
                    }
                }
                const float v0 = m2a[r] + (p0 - m2a[r]) * 0.5f;
                const bool s0 = (v0 - 1.0f) > 0.0f;
                m2a[r] = s0 ? 0.0f : v0;
                const unsigned long long k0 = __ballot(s0);
                const float v1 = m2b[r] + (p1 - m2b[r]) * 0.5f;
                const bool s1 = (v1 - 1.0f) > 0.0f;
                m2b[r] = s1 ? 0.0f : v1;
                const unsigned long long k1 = __ballot(s1);
                if (lane == 0) {
                    bits2[r][wave] = k0; bits2[r][4 + wave] = k1;
                    if (k0 | k1) atomicOr(&rowflag[1], 1u << r);
                }
            }
        }
        __syncthreads();                                   // barrier B
        if (tid == 0) rowflag[0] = 0u;

        // ===== layer 3 (dcn): G d1-part + sparse bits2 -> bits3 ===============
        {
            const unsigned int rf = rowflag[1];
#pragma unroll
            for (int r = 0; r < R2; ++r) {
                float p0 = g2[r] + bd0, p1 = g3[r] + bd1v;
                if (rf & (1u << r)) {
#pragma unroll 1
                    for (int w = 0; w < 8; ++w) {
                        unsigned long long mm = bits2[r][w];
                        while (mm) {
                            const int b = __builtin_ctzll(mm); mm &= (mm - 1);
                            const float* wp = Wd1 + (size_t)(DD + (w << 6) + b) * HIDN + tid;
                            p0 += wp[0]; p1 += wp[256];
                        }
                    }
                }
                const float v0 = m3a[r] + (p0 - m3a[r]) * 0.5f;
                const bool s0 = (v0 - 1.0f) > 0.0f;
                m3a[r] = s0 ? 0.0f : v0;
                const unsigned long long k0 = __ballot(s0);
                const float v1 = m3b[r] + (p1 - m3b[r]) * 0.5f;
                const bool s1 = (v1 - 1.0f) > 0.0f;
                m3b[r] = s1 ? 0.0f : v1;
                const unsigned long long k1 = __ballot(s1);
                if (lane == 0) {
                    bits3[r][wave] = k0; bits3[r][4 + wave] = k1;
                    if (k0 | k1) atomicOr(&rowflag[2], 1u << r);
                }
            }
        }
        __syncthreads();                                   // barrier C
        if (tid == 0) rowflag[1] = 0u;

        // ===== output accumulation over s3 spikes =============================
        {
            const unsigned int rf = rowflag[2];
            if (owrite && (rf & (1u << orow))) {
#pragma unroll 1
                for (int w = 0; w < 8; ++w) {
                    unsigned long long mm = bits3[orow][w];
                    while (mm) {
                        const int b = __builtin_ctzll(mm); mm &= (mm - 1);
                        out_acc += Wd2[(size_t)((w << 6) + b) * OUTN + ocol];
                    }
                }
            }
        }
        // barrier A(t+1) orders these reads vs next overwrites of bits3/flags
    }

    if (owrite)
        out[((size_t)c0 + row0l + orow) * OUTN + ocol] = out_acc * 0.0625f + bd2[ocol];
}

// ---- Fallback: round-0 fused kernel (harness-verified, needs no workspace) ---
__global__ __launch_bounds__(256, 2)
void snn_fused_fb(const float* __restrict__ x,
                  const float* __restrict__ Wgc, const float* __restrict__ bgc,
                  const float* __restrict__ Wpc, const float* __restrict__ bpc,
                  const float* __restrict__ Wd1, const float* __restrict__ bd1p,
                  const float* __restrict__ Wd2, const float* __restrict__ bd2,
                  float* __restrict__ out, int B)
{
    __shared__ float xs[16 * DD];
    __shared__ unsigned long long bits1[16][8];
    __shared__ unsigned long long bits2[16][8];
    __shared__ unsigned long long bits3[16][8];
    __shared__ unsigned int rowflag[3];

    const int tid  = threadIdx.x;
    const int lane = tid & 63;
    const int wave = tid >> 6;
    const size_t row0 = (size_t)blockIdx.x * 16;

    float m1a[16], m1b[16], m2a[16], m2b[16], m3a[16], m3b[16];
#pragma unroll
    for (int r = 0; r < 16; ++r) {
        m1a[r] = 0.f; m1b[r] = 0.f; m2a[r] = 0.f;
        m2b[r] = 0.f; m3a[r] = 0.f; m3b[r] = 0.f;
    }

    const float bg0 = bgc[tid],  bg1 = bgc[tid + 256];
    const float bp0 = bpc[tid],  bp1 = bpc[tid + 256];
    const float bd0 = bd1p[tid], bd1 = bd1p[tid + 256];

    float out_acc = 0.f;
    const int orow = tid / OUTN;
    const int ocol = tid - orow * OUTN;
    const bool owrite = (tid < 16 * OUTN);

    if (tid < 3) rowflag[tid] = 0;
    {
        const float* src = x + row0 * DD;
#pragma unroll
        for (int u = 0; u < 8; ++u)
            GLD_LDS(src + ((u * 256 + tid) << 2), xs + ((u * 256 + wave * 64) << 2));
    }
    __syncthreads();

    for (int t = 0; t < TT; ++t) {
        float a0[16], a1[16], a2[16], a3[16];
#pragma unroll
        for (int r = 0; r < 16; ++r) { a0[r] = 0.f; a1[r] = 0.f; a2[r] = 0.f; a3[r] = 0.f; }

        const float* gp = Wgc + tid;
        const float* dp = Wd1 + tid;

        float wA0[4], wA1[4], wA2[4], wA3[4];
        float wB0[4], wB1[4], wB2[4], wB3[4];
#pragma unroll
        for (int u = 0; u < 4; ++u) {
            const size_t o = (size_t)u * HIDN;
            wA0[u] = gp[o]; wA1[u] = gp[o + 256];
            wA2[u] = dp[o]; wA3[u] = dp[o + 256];
        }
#pragma unroll 1
        for (int kk = 0; kk < DD; kk += 8) {
#pragma unroll
            for (int u = 0; u < 4; ++u) {
                const size_t o = (size_t)(kk + 4 + u) * HIDN;
                wB0[u] = gp[o]; wB1[u] = gp[o + 256];
                wB2[u] = dp[o]; wB3[u] = dp[o + 256];
            }
#pragma unroll
            for (int r = 0; r < 16; ++r) {
                const float4 xv = *reinterpret_cast<const float4*>(&xs[r * DD + kk]);
                a0[r] = fmaf(xv.x, wA0[0], a0[r]); a0[r] = fmaf(xv.y, wA0[1], a0[r]);
                a0[r] = fmaf(xv.z, wA0[2], a0[r]); a0[r] = fmaf(xv.w, wA0[3], a0[r]);
                a1[r] = fmaf(xv.x, wA1[0], a1[r]); a1[r] = fmaf(xv.y, wA1[1], a1[r]);
                a1[r] = fmaf(xv.z, wA1[2], a1[r]); a1[r] = fmaf(xv.w, wA1[3], a1[r]);
                a2[r] = fmaf(xv.x, wA2[0], a2[r]); a2[r] = fmaf(xv.y, wA2[1], a2[r]);
                a2[r] = fmaf(xv.z, wA2[2], a2[r]); a2[r] = fmaf(xv.w, wA2[3], a2[r]);
                a3[r] = fmaf(xv.x, wA3[0], a3[r]); a3[r] = fmaf(xv.y, wA3[1], a3[r]);
                a3[r] = fmaf(xv.z, wA3[2], a3[r]); a3[r] = fmaf(xv.w, wA3[3], a3[r]);
            }
            const int k2 = (kk + 8) & (DD - 1);
#pragma unroll
            for (int u = 0; u < 4; ++u) {
                const size_t o = (size_t)(k2 + u) * HIDN;
                wA0[u] = gp[o]; wA1[u] = gp[o + 256];
                wA2[u] = dp[o]; wA3[u] = dp[o + 256];
            }
#pragma unroll
            for (int r = 0; r < 16; ++r) {
                const float4 xv = *reinterpret_cast<const float4*>(&xs[r * DD + kk + 4]);
                a0[r] = fmaf(xv.x, wB0[0], a0[r]); a0[r] = fmaf(xv.y, wB0[1], a0[r]);
                a0[r] = fmaf(xv.z, wB0[2], a0[r]); a0[r] = fmaf(xv.w, wB0[3], a0[r]);
                a1[r] = fmaf(xv.x, wB1[0], a1[r]); a1[r] = fmaf(xv.y, wB1[1], a1[r]);
                a1[r] = fmaf(xv.z, wB1[2], a1[r]); a1[r] = fmaf(xv.w, wB1[3], a1[r]);
                a2[r] = fmaf(xv.x, wB2[0], a2[r]); a2[r] = fmaf(xv.y, wB2[1], a2[r]);
                a2[r] = fmaf(xv.z, wB2[2], a2[r]); a2[r] = fmaf(xv.w, wB2[3], a2[r]);
                a3[r] = fmaf(xv.x, wB3[0], a3[r]); a3[r] = fmaf(xv.y, wB3[1], a3[r]);
                a3[r] = fmaf(xv.z, wB3[2], a3[r]); a3[r] = fmaf(xv.w, wB3[3], a3[r]);
            }
        }

#pragma unroll
        for (int r = 0; r < 16; ++r) {
            const float v0 = m1a[r] + ((a0[r] + bg0) - m1a[r]) * 0.5f;
            const bool s0 = (v0 - 1.0f) > 0.0f;
            m1a[r] = s0 ? 0.0f : v0;
            const unsigned long long k0 = __ballot(s0);
            const float v1 = m1b[r] + ((a1[r] + bg1) - m1b[r]) * 0.5f;
            const bool s1 = (v1 - 1.0f) > 0.0f;
            m1b[r] = s1 ? 0.0f : v1;
            const unsigned long long k1 = __ballot(s1);
            if (lane == 0) {
                bits1[r][wave] = k0; bits1[r][4 + wave] = k1;
                if (k0 | k1) atomicOr(&rowflag[0], 1u << r);
            }
        }
        __syncthreads();

        if (tid == 0) rowflag[2] = 0;
        if (t + 1 < TT) {
            const float* src = x + (((size_t)(t + 1) * B) + row0) * DD;
#pragma unroll
            for (int u = 0; u < 8; ++u)
                GLD_LDS(src + ((u * 256 + tid) << 2), xs + ((u * 256 + wave * 64) << 2));
        }

        {
            const unsigned int rf = rowflag[0];
#pragma unroll 1
            for (int r = 0; r < 16; ++r) {
                float p0 = bp0, p1 = bp1;
                if (rf & (1u << r)) {
#pragma unroll 1
                    for (int w = 0; w < 8; ++w) {
                        unsigned long long m = bits1[r][w];
                        while (m) {
                            const int b = __builtin_ctzll(m); m &= (m - 1);
                            const float* wp = Wpc + (size_t)((w << 6) + b) * HIDN + tid;
                            p0 += wp[0]; p1 += wp[256];
                        }
                    }
                }
                const float v0 = m2a[r] + (p0 - m2a[r]) * 0.5f;
                const bool s0 = (v0 - 1.0f) > 0.0f;
                m2a[r] = s0 ? 0.0f : v0;
                const unsigned long long k0 = __ballot(s0);
                const float v1 = m2b[r] + (p1 - m2b[r]) * 0.5f;
                const bool s1 = (v1 - 1.0f) > 0.0f;
                m2b[r] = s1 ? 0.0f : v1;
                const unsigned long long k1 = __ballot(s1);
                if (lane == 0) {
                    bits2[r][wave] = k0; bits2[r][4 + wave] = k1;
                    if (k0 | k1) atomicOr(&rowflag[1], 1u << r);
                }
            }
        }
        __syncthreads();

        if (tid == 0) rowflag[0] = 0;

        {
            const unsigned int rf = rowflag[1];
#pragma unroll 1
            for (int r = 0; r < 16; ++r) {
                float p0 = a2[r] + bd0, p1 = a3[r] + bd1;
                if (rf & (1u << r)) {
#pragma unroll 1
                    for (int w = 0; w < 8; ++w) {
                        unsigned long long m = bits2[r][w];
                        while (m) {
                            const int b = __builtin_ctzll(m); m &= (m - 1);
                            const float* wp = Wd1 + (size_t)(DD + (w << 6) + b) * HIDN + tid;
                            p0 += wp[0]; p1 += wp[256];
                        }
                    }
                }
                const float v0 = m3a[r] + (p0 - m3a[r]) * 0.5f;
                const bool s0 = (v0 - 1.0f) > 0.0f;
                m3a[r] = s0 ? 0.0f : v0;
                const unsigned long long k0 = __ballot(s0);
                const float v1 = m3b[r] + (p1 - m3b[r]) * 0.5f;
                const bool s1 = (v1 - 1.0f) > 0.0f;
                m3b[r] = s1 ? 0.0f : v1;
                const unsigned long long k1 = __ballot(s1);
                if (lane == 0) {
                    bits3[r][wave] = k0; bits3[r][4 + wave] = k1;
                    if (k0 | k1) atomicOr(&rowflag[2], 1u << r);
                }
            }
        }
        __syncthreads();

        if (tid == 0) rowflag[1] = 0;

        {
            const unsigned int rf = rowflag[2];
            if (owrite && (rf & (1u << orow))) {
#pragma unroll 1
                for (int w = 0; w < 8; ++w) {
                    unsigned long long m = bits3[orow][w];
                    while (m) {
                        const int b = __builtin_ctzll(m); m &= (m - 1);
                        out_acc += Wd2[(size_t)((w << 6) + b) * OUTN + ocol];
                    }
                }
            }
        }
    }

    if (owrite) out[(row0 + orow) * OUTN + ocol] = out_acc * 0.0625f + bd2[ocol];
}

// Workspace layout (two-phase path): Whi 1 MiB | Wlo 1 MiB | G (TT*chb*NTOT*4)
extern "C" void kernel_launch(void* const* d_in, const int* in_sizes, int n_in,
                              void* d_out, int out_size, void* d_ws, size_t ws_size,
                              hipStream_t stream) {
    const float* x   = (const float*)d_in[0];
    const float* Wgc = (const float*)d_in[1];
    const float* bgc = (const float*)d_in[2];
    const float* Wpc = (const float*)d_in[3];
    const float* bpc = (const float*)d_in[4];
    const float* Wd1 = (const float*)d_in[5];
    const float* bd1 = (const float*)d_in[6];
    const float* Wd2 = (const float*)d_in[7];
    const float* bd2 = (const float*)d_in[8];
    const int B = in_sizes[0] / (TT * DD);

    const size_t wbytes = (size_t)2 << 20;             // packed weights
    // pick largest chunk (power of two, 128..4096) whose G fits the workspace
    int chb = 4096;
    while (chb > 128 &&
           (wbytes + (size_t)TT * chb * NTOT * 4 > ws_size || (B % chb) != 0))
        chb >>= 1;
    const bool twophase =
        d_ws != nullptr &&
        ws_size >= wbytes + (size_t)TT * chb * NTOT * 4 &&
        (B % chb) == 0 && chb >= 128;

    if (!twophase) {
        hipLaunchKernelGGL(snn_fused_fb, dim3(B / 16), dim3(256), 0, stream,
                           x, Wgc, bgc, Wpc, bpc, Wd1, bd1, Wd2, bd2,
                           (float*)d_out, B);
        return;
    }

    _Float16* Whi = reinterpret_cast<_Float16*>(d_ws);
    _Float16* Wlo = Whi + 64 * 16 * 64 * 8;                        // +1 MiB
    float* G = reinterpret_cast<float*>((char*)d_ws + wbytes);     // +2 MiB

    hipLaunchKernelGGL(pack_w, dim3(256), dim3(256), 0, stream, Wgc, Wd1, Whi, Wlo);

    for (int c = 0; c < B; c += chb) {
        hipLaunchKernelGGL(gemm_pre, dim3(8, chb / 128, TT), dim3(256), 0, stream,
                           x, Whi, Wlo, G, B, c, chb);
        hipLaunchKernelGGL(snn_recur, dim3(chb / R2), dim3(256), 0, stream,
                           G, bgc, Wpc, bpc, Wd1, bd1, Wd2, bd2,
                           (float*)d_out, c, chb);
    }
}